// Round 6
// baseline (334.851 us; speedup 1.0000x reference)
//
#include <hip/hip_runtime.h>
#include <math.h>

#define T_DIM 4096
#define TRACE 64
#define CTX   64

typedef float f32x4 __attribute__((ext_vector_type(4)));

// ---------------------------------------------------------------------------
// Kernel A: precompute per-t trig/decay tables (3 MB, L2/L3 resident).
// ---------------------------------------------------------------------------
__global__ __launch_bounds__(256) void ffm_tables(
    const float* __restrict__ a, const float* __restrict__ b,
    const int*   __restrict__ iv, const int* __restrict__ jv,
    float* __restrict__ tcos, float* __restrict__ tsin,
    float* __restrict__ tdec, float* __restrict__ out_cnt)
{
    const int idx = blockIdx.x * 256 + threadIdx.x;  // 0 .. T*64-1
    const int t   = idx >> 6;
    const int k   = idx & 63;
    const float tf = (float)jv[t];
    float s, c;
    sincosf(b[k] * tf, &s, &c);
    tcos[idx] = c;
    tsin[idx] = s;
    tdec[idx] = expf(-fabsf(a[k]) * tf);
    if (k == 0) out_cnt[t] = (float)(jv[t] + iv[t]);
}

// ---------------------------------------------------------------------------
// Kernel B: full-line nontemporal stores.
//   Segment = 256 elements (512 output floats = 128 float4 chunks).
//   Lane l owns output chunks l and l+64 -> each store instruction is
//   lane-contiguous (1 KB, 16 full 64B lines) so nt stores cannot produce
//   partial-line flushes (round-1 failure mode). Matching inputs are
//   lane-contiguous float2 loads (regions A: elems 2l, B: 128+2l).
//   Goal: nt => no L3 allocation for the write stream => input tensors
//   (268 MB) stay L3-resident across bench iterations => FETCH collapses.
// ---------------------------------------------------------------------------
__global__ __launch_bounds__(256) void ffm_main(
    const float* __restrict__ state_re, const float* __restrict__ state_im,
    const float* __restrict__ x_re, const float* __restrict__ x_im,
    const float* __restrict__ tcos, const float* __restrict__ tsin,
    const float* __restrict__ tdec,
    float* __restrict__ out)
{
    const int t = blockIdx.x;
    const int w = threadIdx.x >> 6;     // wave 0..3
    const int l = threadIdx.x & 63;     // lane

    const size_t eb = (size_t)t * (TRACE * CTX);       // element base
    const float2* __restrict__ sre2 = (const float2*)(state_re + eb);
    const float2* __restrict__ sim2 = (const float2*)(state_im + eb);
    const float2* __restrict__ xre2 = (const float2*)(x_re + eb);
    const float2* __restrict__ xim2 = (const float2*)(x_im + eb);
    f32x4* __restrict__ o4 = (f32x4*)(out + eb * 2);   // 2048 chunks per t

    // ctx pair for elements (2l, 2l+1): loop-invariant.
    const float2 vc = ((const float2*)(tcos + t * 64))[l & 31];
    const float2 vs = ((const float2*)(tsin + t * 64))[l & 31];
    const float* td = tdec + t * 64;

    #pragma unroll
    for (int k = 0; k < 4; ++k) {
        const int s  = k * 4 + w;        // segment 0..15 (256 elems each)
        const int i2 = s * 128 + l;      // float2 index, region A; B = +64

        // trace rows: elem_A = s*256 + 2l -> tr = s*4 + (l>>5); B: +2
        const float decA = td[s * 4 + (l >> 5)];
        const float decB = td[s * 4 + 2 + (l >> 5)];

        // lane-contiguous float2 loads (512 B per wave-instruction)
        const float2 ra = sre2[i2], rb = sre2[i2 + 64];
        const float2 ia = sim2[i2], ib = sim2[i2 + 64];
        const float2 xa = xre2[i2], xb = xre2[i2 + 64];
        const float2 ya = xim2[i2], yb = xim2[i2 + 64];

        const float grA0 = decA * vc.x, giA0 = decA * vs.x;
        const float grA1 = decA * vc.y, giA1 = decA * vs.y;
        const float grB0 = decB * vc.x, giB0 = decB * vs.x;
        const float grB1 = decB * vc.y, giB1 = decB * vs.y;

        f32x4 oA, oB;
        oA.x = fmaf(ra.x, grA0, fmaf(-ia.x, giA0, xa.x));
        oA.y = fmaf(ra.x, giA0, fmaf( ia.x, grA0, ya.x));
        oA.z = fmaf(ra.y, grA1, fmaf(-ia.y, giA1, xa.y));
        oA.w = fmaf(ra.y, giA1, fmaf( ia.y, grA1, ya.y));
        oB.x = fmaf(rb.x, grB0, fmaf(-ib.x, giB0, xb.x));
        oB.y = fmaf(rb.x, giB0, fmaf( ib.x, grB0, yb.x));
        oB.z = fmaf(rb.y, grB1, fmaf(-ib.y, giB1, xb.y));
        oB.w = fmaf(rb.y, giB1, fmaf( ib.y, grB1, yb.y));

        // chunk index == i2 by construction: lane-contiguous, full lines.
        __builtin_nontemporal_store(oA, &o4[i2]);
        __builtin_nontemporal_store(oB, &o4[i2 + 64]);
    }
}

// ---------------------------------------------------------------------------
// Fallback (workspace too small): original single-kernel version.
// ---------------------------------------------------------------------------
__global__ __launch_bounds__(256) void ffm_kernel_fallback(
    const float* __restrict__ state_re, const float* __restrict__ state_im,
    const float* __restrict__ x_re, const float* __restrict__ x_im,
    const float* __restrict__ a, const float* __restrict__ b,
    const int* __restrict__ ivec, const int* __restrict__ jvec,
    float* __restrict__ out, float* __restrict__ out_cnt)
{
    const int t   = blockIdx.x;
    const int tid = threadIdx.x;
    const float tf = (float)jvec[t];

    __shared__ float s_cos[CTX];
    __shared__ float s_sin[CTX];
    __shared__ float s_dec[TRACE];

    if (tid < CTX) {
        float theta = b[tid] * tf;
        float s, c;
        sincosf(theta, &s, &c);
        s_cos[tid] = c;
        s_sin[tid] = s;
    } else if (tid < CTX + TRACE) {
        int tr = tid - CTX;
        s_dec[tr] = expf(-fabsf(a[tr]) * tf);
    }
    if (tid == 0) out_cnt[t] = (float)(jvec[t] + ivec[t]);
    __syncthreads();

    const size_t base = (size_t)t * (TRACE * CTX);
    const float4* sre = (const float4*)(state_re + base);
    const float4* sim = (const float4*)(state_im + base);
    const float4* xre = (const float4*)(x_re + base);
    const float4* xim = (const float4*)(x_im + base);
    float4* o = (float4*)(out + base * 2);

    #pragma unroll
    for (int k = 0; k < 4; ++k) {
        const int g  = tid + k * 256;
        const int e  = g * 4;
        const int tr = e >> 6;
        const int c0 = e & 63;

        const float dec = s_dec[tr];
        const float4 vre = sre[g];
        const float4 vim = sim[g];
        const float4 vxr = xre[g];
        const float4 vxi = xim[g];

        const float gr0 = dec * s_cos[c0 + 0], gi0 = dec * s_sin[c0 + 0];
        const float gr1 = dec * s_cos[c0 + 1], gi1 = dec * s_sin[c0 + 1];
        const float gr2 = dec * s_cos[c0 + 2], gi2 = dec * s_sin[c0 + 2];
        const float gr3 = dec * s_cos[c0 + 3], gi3 = dec * s_sin[c0 + 3];

        float4 o0, o1;
        o0.x = fmaf(vre.x, gr0, fmaf(-vim.x, gi0, vxr.x));
        o0.y = fmaf(vre.x, gi0, fmaf( vim.x, gr0, vxi.x));
        o0.z = fmaf(vre.y, gr1, fmaf(-vim.y, gi1, vxr.y));
        o0.w = fmaf(vre.y, gi1, fmaf( vim.y, gr1, vxi.y));
        o1.x = fmaf(vre.z, gr2, fmaf(-vim.z, gi2, vxr.z));
        o1.y = fmaf(vre.z, gi2, fmaf( vim.z, gr2, vxi.z));
        o1.z = fmaf(vre.w, gr3, fmaf(-vim.w, gi3, vxr.w));
        o1.w = fmaf(vre.w, gi3, fmaf( vim.w, gr3, vxi.w));

        o[2 * g + 0] = o0;
        o[2 * g + 1] = o1;
    }
}

extern "C" void kernel_launch(void* const* d_in, const int* in_sizes, int n_in,
                              void* d_out, int out_size, void* d_ws, size_t ws_size,
                              hipStream_t stream) {
    const float* state_re = (const float*)d_in[0];
    const float* state_im = (const float*)d_in[1];
    const float* x_re     = (const float*)d_in[2];
    const float* x_im     = (const float*)d_in[3];
    const float* a        = (const float*)d_in[4];
    const float* b        = (const float*)d_in[5];
    const int*   iv       = (const int*)d_in[6];
    const int*   jv       = (const int*)d_in[7];

    float* out     = (float*)d_out;
    float* out_cnt = out + (size_t)T_DIM * TRACE * CTX * 2;

    const size_t tab_elems = (size_t)T_DIM * 64;       // 262144 per table
    const size_t need = 3 * tab_elems * sizeof(float); // 3 MB

    if (ws_size >= need) {
        float* tcos = (float*)d_ws;
        float* tsin = tcos + tab_elems;
        float* tdec = tsin + tab_elems;

        ffm_tables<<<T_DIM * 64 / 256, 256, 0, stream>>>(
            a, b, iv, jv, tcos, tsin, tdec, out_cnt);
        ffm_main<<<T_DIM, 256, 0, stream>>>(
            state_re, state_im, x_re, x_im, tcos, tsin, tdec, out);
    } else {
        ffm_kernel_fallback<<<T_DIM, 256, 0, stream>>>(
            state_re, state_im, x_re, x_im, a, b, iv, jv, out, out_cnt);
    }
}

// Round 7
// 326.439 us; speedup vs baseline: 1.0258x; 1.0258x over previous
//
#include <hip/hip_runtime.h>
#include <math.h>

#define T_DIM 4096
#define TRACE 64
#define CTX 64

// One block per t. Precompute per-t trig (64 ctx values) and decay (64 trace
// values) in LDS, then do the elementwise complex MAD with float4 loads/stores.
// Memory-bound: 268 MB in + 134 MB out ~= 402 MB.
// Measured plateau: ~113 us main kernel, ~2.4 TB/s HBM-visible.
// Six structural variants (grid-stride, table-fed, batched loads, burst
// remap, nt stores) all land within noise of this version; the limit is the
// memory-side MALL write-allocate churn (FETCH~=WRITE steady state), not
// wave-side scheduling.
__global__ __launch_bounds__(256) void ffm_kernel(
    const float* __restrict__ state_re,
    const float* __restrict__ state_im,
    const float* __restrict__ x_re,
    const float* __restrict__ x_im,
    const float* __restrict__ a,
    const float* __restrict__ b,
    const int*   __restrict__ ivec,
    const int*   __restrict__ jvec,
    float* __restrict__ out,       // [T, TRACE, CTX, 2] interleaved re/im
    float* __restrict__ out_cnt)   // [T] (j+i) stored as float values
{
    const int t   = blockIdx.x;
    const int tid = threadIdx.x;
    const float tf = (float)jvec[t];

    __shared__ float s_cos[CTX];
    __shared__ float s_sin[CTX];
    __shared__ float s_dec[TRACE];

    if (tid < CTX) {
        float theta = b[tid] * tf;
        float s, c;
        sincosf(theta, &s, &c);      // accurate: only 64 per block
        s_cos[tid] = c;
        s_sin[tid] = s;
    } else if (tid < CTX + TRACE) {
        int tr = tid - CTX;
        s_dec[tr] = expf(-fabsf(a[tr]) * tf);
    }
    if (tid == 0) {
        out_cnt[t] = (float)(jvec[t] + ivec[t]);
    }
    __syncthreads();

    const size_t base = (size_t)t * (TRACE * CTX);
    const float4* sre = (const float4*)(state_re + base);
    const float4* sim = (const float4*)(state_im + base);
    const float4* xre = (const float4*)(x_re + base);
    const float4* xim = (const float4*)(x_im + base);
    float4* o = (float4*)(out + base * 2);

    // 4096 elements per t = 1024 float4 groups; 256 threads -> 4 groups each.
    #pragma unroll
    for (int k = 0; k < 4; ++k) {
        const int g  = tid + k * 256;   // float4 group index, 0..1023
        const int e  = g * 4;           // element index within [TRACE*CTX]
        const int tr = e >> 6;          // all 4 elems share trace row (CTX=64)
        const int c0 = e & 63;

        const float dec = s_dec[tr];
        const float4 vre = sre[g];
        const float4 vim = sim[g];
        const float4 vxr = xre[g];
        const float4 vxi = xim[g];

        const float gr0 = dec * s_cos[c0 + 0], gi0 = dec * s_sin[c0 + 0];
        const float gr1 = dec * s_cos[c0 + 1], gi1 = dec * s_sin[c0 + 1];
        const float gr2 = dec * s_cos[c0 + 2], gi2 = dec * s_sin[c0 + 2];
        const float gr3 = dec * s_cos[c0 + 3], gi3 = dec * s_sin[c0 + 3];

        float4 o0, o1;
        // elems 0,1 -> o0 ; elems 2,3 -> o1 (re,im interleaved)
        o0.x = fmaf(vre.x, gr0, fmaf(-vim.x, gi0, vxr.x));
        o0.y = fmaf(vre.x, gi0, fmaf( vim.x, gr0, vxi.x));
        o0.z = fmaf(vre.y, gr1, fmaf(-vim.y, gi1, vxr.y));
        o0.w = fmaf(vre.y, gi1, fmaf( vim.y, gr1, vxi.y));
        o1.x = fmaf(vre.z, gr2, fmaf(-vim.z, gi2, vxr.z));
        o1.y = fmaf(vre.z, gi2, fmaf( vim.z, gr2, vxi.z));
        o1.z = fmaf(vre.w, gr3, fmaf(-vim.w, gi3, vxr.w));
        o1.w = fmaf(vre.w, gi3, fmaf( vim.w, gr3, vxi.w));

        o[2 * g + 0] = o0;
        o[2 * g + 1] = o1;
    }
}

extern "C" void kernel_launch(void* const* d_in, const int* in_sizes, int n_in,
                              void* d_out, int out_size, void* d_ws, size_t ws_size,
                              hipStream_t stream) {
    const float* state_re = (const float*)d_in[0];
    const float* state_im = (const float*)d_in[1];
    const float* x_re     = (const float*)d_in[2];
    const float* x_im     = (const float*)d_in[3];
    const float* a        = (const float*)d_in[4];
    const float* b        = (const float*)d_in[5];
    const int*   iv       = (const int*)d_in[6];
    const int*   jv       = (const int*)d_in[7];

    float* out     = (float*)d_out;
    float* out_cnt = out + (size_t)T_DIM * TRACE * CTX * 2;

    ffm_kernel<<<T_DIM, 256, 0, stream>>>(state_re, state_im, x_re, x_im,
                                          a, b, iv, jv, out, out_cnt);
}